// Round 8
// baseline (5039.912 us; speedup 1.0000x reference)
//
#include <hip/hip_runtime.h>

#define TT 20
#define FF 8
#define HH 256
#define PP 15
#define DP 64
#define ROWS 32
#define NTHR 512
#define NBLK 256

typedef __attribute__((ext_vector_type(8))) _Float16 hfrag;  // 8 x f16 (4 VGPR)
typedef __attribute__((ext_vector_type(16))) float f32x16;   // MFMA 32x32 acc
typedef __attribute__((ext_vector_type(4))) float f32x4;

// XOR swizzle on element index (units of 8 elems = 16B) for h tiles in LDS.
__device__ __forceinline__ int sw(int row, int k, int w){
  return (row * w + k) ^ ((row & 7) << 3);
}
__device__ __forceinline__ f32x16 zero16(){
  f32x16 v;
  #pragma unroll
  for (int i = 0; i < 16; ++i) v[i] = 0.f;
  return v;
}

// ---- pre-pass: convert fp32 weights to SINGLE-plane f16 (2^-11 rel err),
// stored in wave-coalesced MFMA-fragment order:
//   ws[wgkc*512 + (lkh*32+lcol)*8 + e] = W^T[g*256+wid*32+lcol][kc*16+lkh*8+e]
// so a B-fragment load is lane-contiguous 16B -> one coalesced 1KB wave txn.
__global__ void wprep(const float* __restrict__ ek, const float* __restrict__ erk,
                      const float* __restrict__ dk, const float* __restrict__ drk,
                      _Float16* __restrict__ ws){
  int i = blockIdx.x * 256 + threadIdx.x;       // 53248 total
  const float* src; _Float16* dst; int ksh, rel;
  if (i < 4096)        { src = ek;  ksh = 2; rel = i;          dst = ws;           }
  else if (i < 20480)  { src = erk; ksh = 4; rel = i - 4096;   dst = ws + 65536;   }
  else if (i < 36864)  { src = dk;  ksh = 4; rel = i - 20480;  dst = ws + 327680;  }
  else                 { src = drk; ksh = 4; rel = i - 36864;  dst = ws + 589824;  }
  int lcol = rel & 31;
  int gkc  = rel >> 5;                // (wid*4+g)*NKC + kc
  int kc   = gkc & ((1 << ksh) - 1);
  int wg   = gkc >> ksh;              // wid*4 + g
  int g    = wg & 3, wid = wg >> 2;
  int col  = g * 256 + wid * 32 + lcol;          // n index in source (k*1024+n)
  int base = gkc * 512;
  #pragma unroll
  for (int lkh = 0; lkh < 2; ++lkh){
    _Float16 hbuf[8];
    #pragma unroll
    for (int e = 0; e < 8; ++e){
      int k = kc * 16 + lkh * 8 + e;
      hbuf[e] = (_Float16)src[k * 1024 + col];   // lane-coalesced read, RTNE cvt
    }
    int off = base + (lkh * 32 + lcol) * 8;      // lane-coalesced 16B stores
    *reinterpret_cast<hfrag*>(&dst[off]) = *reinterpret_cast<hfrag*>(hbuf);
  }
}

// K-sweep of ACC += A @ W for all 4 gate tiles, single-f16: 1 MFMA / gate / kc.
// kc and g are ROTATED by block-dependent offsets (bofs/gofs): accumulation is
// order-independent, and the rotation de-synchronizes the 32 same-XCD blocks'
// otherwise-lockstep reads of identical weight addresses (L2 bank hotspot).
#define MM_STEPA(ACC, HSRC, WT, KD, NKC)                                                     \
  { const _Float16* ph = (WT) + (wid * 4 * (NKC)) * 512 + lane * 8;                          \
    _Pragma("unroll 4")                                                                      \
    for (int kci = 0; kci < (NKC); ++kci){                                                   \
      int kc = (kci + bofs) & ((NKC) - 1);                                                   \
      int k0 = kc * 16 + lkh * 8;                                                            \
      hfrag a = *reinterpret_cast<const hfrag*>(&(HSRC)[sw(lcol, k0, (KD))]);                \
      _Pragma("unroll")                                                                      \
      for (int gi = 0; gi < 4; ++gi){                                                        \
        int g = (gi + gofs) & 3;                                                             \
        hfrag b = *reinterpret_cast<const hfrag*>(ph + (g * (NKC) + kc) * 512);              \
        ACC[g] = __builtin_amdgcn_mfma_f32_32x32x16_f16(a, b, ACC[g], 0, 0, 0);              \
      }                                                                                      \
    }                                                                                        \
  }

// lane-local gate math (4 exp + 3 rcp via shared denominators); writes new h
// (single f16) to swizzled LDS.
#define GATE_UPDATE(HDST, B0, B1, B2, B3, DOZERO)                                            \
  { _Pragma("unroll")                                                                        \
    for (int rg = 0; rg < 16; ++rg){                                                         \
      float zi = acc[0][rg] + (B0);                                                          \
      float zf = acc[1][rg] + (B1);                                                          \
      float zg = acc[2][rg] + (B2);                                                          \
      float zo = acc[3][rg] + (B3);                                                          \
      float ei = __expf(-zi), ef = __expf(-zf), eo = __expf(-zo);                            \
      float eg = __expf(2.f * zg);                                                           \
      float r1 = __builtin_amdgcn_rcpf(1.f + ef);                                            \
      float r2 = __builtin_amdgcn_rcpf((1.f + ei) * (eg + 1.f));                             \
      float cv = cst[rg] * r1 + (eg - 1.f) * r2;   /* f*c + i*tanh(g) */                     \
      cst[rg] = cv;                                                                          \
      float ec = __expf(2.f * cv);                                                           \
      float r3 = __builtin_amdgcn_rcpf((1.f + eo) * (ec + 1.f));                             \
      float hv = (ec - 1.f) * r3;                  /* o*tanh(c) */                           \
      int row = (rg & 3) + 8 * (rg >> 2) + 4 * lkh;                                          \
      (HDST)[sw(row, j, HH)] = (_Float16)hv;                                                 \
    }                                                                                        \
    if (DOZERO){ _Pragma("unroll") for (int g = 0; g < 4; ++g) acc[g] = zero16(); }          \
  }

// xp_t = relu(x_t @ w_in_k + b) -> f16 into xb buffer `buf`.
#define STAGE_XP(tt, buf)                                                                    \
  { _Pragma("unroll")                                                                        \
    for (int rr = 0; rr < 4; ++rr){                                                          \
      int row = rb + 8 * rr;                                                                 \
      const float* xr = x + ((long)(r0 + row) * TT + (tt)) * FF;                             \
      f32x4 xa = *reinterpret_cast<const f32x4*>(xr);                                        \
      f32x4 xv = *reinterpret_cast<const f32x4*>(xr + 4);                                    \
      float s = bwin;                                                                        \
      _Pragma("unroll")                                                                      \
      for (int f = 0; f < 4; ++f){                                                           \
        s += xa[f] * winK[f * DP + xc];                                                      \
        s += xv[f] * winK[(f + 4) * DP + xc];                                                \
      }                                                                                      \
      s = fmaxf(s, 0.f);                                                                     \
      xb[buf][sw(row, xc, DP)] = (_Float16)s;                                                \
    } }

// output heads, parallel over all 512 threads: 4 partial-K threads per output,
// reduced via shfl_xor over lane bits 2..3.
#define OUT_HEAD(tt)                                                                         \
  { float s = 0.f;                                                                           \
    _Pragma("unroll")                                                                        \
    for (int kb = 0; kb < 8; ++kb){                                                          \
      int k0 = sub_o * 64 + kb * 8;                                                          \
      hfrag vh = *reinterpret_cast<const hfrag*>(&h2[sw(orow_o, k0, HH)]);                   \
      _Pragma("unroll")                                                                      \
      for (int q = 0; q < 8; ++q){                                                           \
        s += (float)vh[q] * whead[(k0 + q) * 4 + ooc_o];                                     \
      }                                                                                      \
    }                                                                                        \
    s += __shfl_xor(s, 4);                                                                   \
    s += __shfl_xor(s, 8);                                                                   \
    if (sub_o == 0){                                                                         \
      s += hbias;                                                                            \
      if (ooc_o >= 2) s = fmaxf(s, 0.f);                                                     \
      out[(long)(r0 + orow_o) * (PP * 4) + (tt) * 4 + ooc_o] = s;                            \
    } }

// (512,1): do NOT cap VGPRs — occupancy is 1 block/CU (grid == CU count);
// acc[4]+accD[4] = 128 AGPRs + arch regs fit the 2-waves/SIMD unified budget.
__global__ __launch_bounds__(NTHR, 1) void lstm_main(
    const float* __restrict__ x,
    const float* __restrict__ w_in_k,
    const float* __restrict__ w_in_b,
    const float* __restrict__ enc_b,
    const float* __restrict__ dec_b,
    const float* __restrict__ mean_k,
    const float* __restrict__ mean_b,
    const float* __restrict__ lv_k,
    const float* __restrict__ lv_b,
    const _Float16* __restrict__ ws,
    float* __restrict__ out)
{
  __shared__ _Float16 h1[ROWS * HH];      // encoder h -> frozen enc output (16 KB)
  __shared__ _Float16 h2[ROWS * HH];      // decoder h (16 KB)
  __shared__ _Float16 xb[2][ROWS * DP];   // xp double buffer (8 KB)
  __shared__ float winK[FF * DP];
  __shared__ float whead[HH * 4];         // [k][mean0,mean1,lv0,lv1]

  const int tid  = threadIdx.x;
  const int wid  = tid >> 6;        // wave id = column-quarter (0..7)
  const int lane = tid & 63;
  const int lcol = lane & 31;       // A-row / B-col within 32-tile
  const int lkh  = lane >> 5;       // k-half of fragment
  const int j    = wid * 32 + lcol; // hidden col 0..255 owned by this lane
  const int r0   = blockIdx.x * ROWS;
  // same-XCD blocks (blockIdx%8 == XCD) get 16 distinct K-sweep offsets:
  const int bofs = (blockIdx.x >> 3) & 15;
  const int gofs = (blockIdx.x >> 7) & 3;

  const _Float16* enckT  = ws;
  const _Float16* encrkT = ws + 65536;
  const _Float16* deckT  = ws + 327680;
  const _Float16* decrkT = ws + 589824;

  if (tid < FF * DP) winK[tid] = w_in_k[tid];
  if (tid >= 256){
    int k = tid - 256;
    whead[k * 4 + 0] = mean_k[k * 2 + 0];
    whead[k * 4 + 1] = mean_k[k * 2 + 1];
    whead[k * 4 + 2] = lv_k[k * 2 + 0];
    whead[k * 4 + 3] = lv_k[k * 2 + 1];
  }

  const int xc = tid & 63;          // xp column this thread produces
  const int rb = tid >> 6;          // xp row base
  const float bwin = w_in_b[xc];

  const int orow_o = tid >> 4;      // out-head mapping (all 512 threads)
  const int sub_o  = (tid >> 2) & 3;
  const int ooc_o  = tid & 3;
  const float hbias = (ooc_o < 2) ? mean_b[ooc_o] : lv_b[ooc_o - 2];

  const float eb0 = enc_b[0 * HH + j], eb1 = enc_b[1 * HH + j];
  const float eb2 = enc_b[2 * HH + j], eb3 = enc_b[3 * HH + j];
  const float db0 = dec_b[0 * HH + j], db1 = dec_b[1 * HH + j];
  const float db2 = dec_b[2 * HH + j], db3 = dec_b[3 * HH + j];

  f32x16 acc[4];    // per-gate accumulators (32x32 tile)
  f32x16 accD[4];   // decoder constant-input term (enc_h @ dec_k), registers
  float  cst[16];   // lane-local LSTM cell state
  #pragma unroll
  for (int g = 0; g < 4; ++g) acc[g] = zero16();
  #pragma unroll
  for (int r = 0; r < 16; ++r) cst[r] = 0.f;

  __syncthreads();
  STAGE_XP(0, 0);
  __syncthreads();

  // ---------------- encoder: 20 steps ----------------
  for (int t = 0; t < TT; ++t){
    MM_STEPA(acc, xb[t & 1], enckT, DP, 4);            // xp_t @ enc_k
    if (t > 0){
      MM_STEPA(acc, h1, encrkT, HH, 16);               // h @ enc_rk
    }
    if (t + 1 < TT) STAGE_XP(t + 1, (t + 1) & 1);      // overlaps with MFMA above
    __syncthreads();                                    // h reads done; xp ready
    GATE_UPDATE(h1, eb0, eb1, eb2, eb3, 1);
    __syncthreads();                                    // new h visible
  }

  // ---------------- decoder: 15 steps ----------------
  // RepeatVector: input term enc_h @ dec_k is constant -> compute once into
  // registers (accD), reused all 15 steps.
  #pragma unroll
  for (int g = 0; g < 4; ++g) accD[g] = zero16();
  {
    f32x16* acc = accD;   // alias so MM_STEPA targets accD
    MM_STEPA(acc, h1, deckT, HH, 16);
  }
  #pragma unroll
  for (int r = 0; r < 16; ++r) cst[r] = 0.f;

  for (int t = 0; t < PP; ++t){
    if (t > 0) OUT_HEAD(t - 1);                        // overlaps rk MFMA (read-read on h2)
    #pragma unroll
    for (int g = 0; g < 4; ++g) acc[g] = accD[g];
    if (t > 0){
      MM_STEPA(acc, h2, decrkT, HH, 16);               // h @ dec_rk
    }
    __syncthreads();
    GATE_UPDATE(h2, db0, db1, db2, db3, 0);
    __syncthreads();
  }
  OUT_HEAD(PP - 1);
}

extern "C" void kernel_launch(void* const* d_in, const int* in_sizes, int n_in,
                              void* d_out, int out_size, void* d_ws, size_t ws_size,
                              hipStream_t stream)
{
  const float* x      = (const float*)d_in[0];
  const float* w_in_k = (const float*)d_in[1];
  const float* w_in_b = (const float*)d_in[2];
  const float* enc_k  = (const float*)d_in[3];
  const float* enc_rk = (const float*)d_in[4];
  const float* enc_b  = (const float*)d_in[5];
  const float* dec_k  = (const float*)d_in[6];
  const float* dec_rk = (const float*)d_in[7];
  const float* dec_b  = (const float*)d_in[8];
  const float* mean_k = (const float*)d_in[9];
  const float* mean_b = (const float*)d_in[10];
  const float* lv_k   = (const float*)d_in[11];
  const float* lv_b   = (const float*)d_in[12];
  _Float16* ws        = (_Float16*)d_ws;

  if (ws_size < 1703936) return;   // 851968 f16 weights = 1.625 MB scratch

  wprep<<<dim3(208), dim3(256), 0, stream>>>(enc_k, enc_rk, dec_k, dec_rk, ws);
  lstm_main<<<dim3(NBLK), dim3(NTHR), 0, stream>>>(x, w_in_k, w_in_b, enc_b, dec_b,
                                                   mean_k, mean_b, lv_k, lv_b, ws,
                                                   (float*)d_out);
}

// Round 9
// 350.799 us; speedup vs baseline: 14.3670x; 14.3670x over previous
//
#include <hip/hip_runtime.h>

#define TT 20
#define FF 8
#define HH 256
#define PP 15
#define DP 64
#define ROWS 32
#define NTHR 512
#define NBLK 256

typedef __attribute__((ext_vector_type(8))) _Float16 hfrag;  // 8 x f16 (4 VGPR)
typedef __attribute__((ext_vector_type(16))) float f32x16;   // MFMA 32x32 acc
typedef __attribute__((ext_vector_type(4))) float f32x4;

// XOR swizzle on element index (units of 8 elems = 16B) for h tiles in LDS.
__device__ __forceinline__ int sw(int row, int k, int w){
  return (row * w + k) ^ ((row & 7) << 3);
}
__device__ __forceinline__ f32x16 zero16(){
  f32x16 v;
  #pragma unroll
  for (int i = 0; i < 16; ++i) v[i] = 0.f;
  return v;
}

// ---- pre-pass: convert fp32 weights to SINGLE-plane f16 (2^-11 rel err),
// stored in wave-coalesced MFMA-fragment order:
//   ws[wgkc*512 + (lkh*32+lcol)*8 + e] = W^T[g*256+wid*32+lcol][kc*16+lkh*8+e]
// so a B-fragment load is lane-contiguous 16B -> one coalesced 1KB wave txn.
__global__ void wprep(const float* __restrict__ ek, const float* __restrict__ erk,
                      const float* __restrict__ dk, const float* __restrict__ drk,
                      _Float16* __restrict__ ws){
  int i = blockIdx.x * 256 + threadIdx.x;       // 53248 total
  const float* src; _Float16* dst; int ksh, rel;
  if (i < 4096)        { src = ek;  ksh = 2; rel = i;          dst = ws;           }
  else if (i < 20480)  { src = erk; ksh = 4; rel = i - 4096;   dst = ws + 65536;   }
  else if (i < 36864)  { src = dk;  ksh = 4; rel = i - 20480;  dst = ws + 327680;  }
  else                 { src = drk; ksh = 4; rel = i - 36864;  dst = ws + 589824;  }
  int lcol = rel & 31;
  int gkc  = rel >> 5;                // (wid*4+g)*NKC + kc
  int kc   = gkc & ((1 << ksh) - 1);
  int wg   = gkc >> ksh;              // wid*4 + g
  int g    = wg & 3, wid = wg >> 2;
  int col  = g * 256 + wid * 32 + lcol;          // n index in source (k*1024+n)
  int base = gkc * 512;
  #pragma unroll
  for (int lkh = 0; lkh < 2; ++lkh){
    _Float16 hbuf[8];
    #pragma unroll
    for (int e = 0; e < 8; ++e){
      int k = kc * 16 + lkh * 8 + e;
      hbuf[e] = (_Float16)src[k * 1024 + col];   // lane-coalesced read, RTNE cvt
    }
    int off = base + (lkh * 32 + lcol) * 8;      // lane-coalesced 16B stores
    *reinterpret_cast<hfrag*>(&dst[off]) = *reinterpret_cast<hfrag*>(hbuf);
  }
}

// K-sweep of ACC += A @ W for all 4 gate tiles, single-f16: 1 MFMA / gate / kc.
// NOTE (R8 lesson, rule #20): ACC index g MUST be compile-time constant —
// runtime-rotated acc indices demote accumulators to scratch (2 GB traffic).
#define MM_STEPA(ACC, HSRC, WT, KD, NKC)                                                     \
  { const _Float16* ph = (WT) + (wid * 4 * (NKC)) * 512 + lane * 8;                          \
    _Pragma("unroll 4")                                                                      \
    for (int kc = 0; kc < (NKC); ++kc){                                                      \
      int k0 = kc * 16 + lkh * 8;                                                            \
      hfrag a = *reinterpret_cast<const hfrag*>(&(HSRC)[sw(lcol, k0, (KD))]);                \
      _Pragma("unroll")                                                                      \
      for (int g = 0; g < 4; ++g){                                                           \
        hfrag b = *reinterpret_cast<const hfrag*>(ph + (g * (NKC) + kc) * 512);              \
        ACC[g] = __builtin_amdgcn_mfma_f32_32x32x16_f16(a, b, ACC[g], 0, 0, 0);              \
      }                                                                                      \
    }                                                                                      \
  }

// lane-local gate math (5 exp + 3 rcp via shared denominators); writes new h
// (single f16) to swizzled LDS.
#define GATE_UPDATE(HDST, B0, B1, B2, B3, DOZERO)                                            \
  { _Pragma("unroll")                                                                        \
    for (int rg = 0; rg < 16; ++rg){                                                         \
      float zi = acc[0][rg] + (B0);                                                          \
      float zf = acc[1][rg] + (B1);                                                          \
      float zg = acc[2][rg] + (B2);                                                          \
      float zo = acc[3][rg] + (B3);                                                          \
      float ei = __expf(-zi), ef = __expf(-zf), eo = __expf(-zo);                            \
      float eg = __expf(2.f * zg);                                                           \
      float r1 = __builtin_amdgcn_rcpf(1.f + ef);                                            \
      float r2 = __builtin_amdgcn_rcpf((1.f + ei) * (eg + 1.f));                             \
      float cv = cst[rg] * r1 + (eg - 1.f) * r2;   /* f*c + i*tanh(g) */                     \
      cst[rg] = cv;                                                                          \
      float ec = __expf(2.f * cv);                                                           \
      float r3 = __builtin_amdgcn_rcpf((1.f + eo) * (ec + 1.f));                             \
      float hv = (ec - 1.f) * r3;                  /* o*tanh(c) */                           \
      int row = (rg & 3) + 8 * (rg >> 2) + 4 * lkh;                                          \
      (HDST)[sw(row, j, HH)] = (_Float16)hv;                                                 \
    }                                                                                        \
    if (DOZERO){ _Pragma("unroll") for (int g = 0; g < 4; ++g) acc[g] = zero16(); }          \
  }

// xp_t = relu(x_t @ w_in_k + b) -> f16 into xb buffer `buf`.
#define STAGE_XP(tt, buf)                                                                    \
  { _Pragma("unroll")                                                                        \
    for (int rr = 0; rr < 4; ++rr){                                                          \
      int row = rb + 8 * rr;                                                                 \
      const float* xr = x + ((long)(r0 + row) * TT + (tt)) * FF;                             \
      f32x4 xa = *reinterpret_cast<const f32x4*>(xr);                                        \
      f32x4 xv = *reinterpret_cast<const f32x4*>(xr + 4);                                    \
      float s = bwin;                                                                        \
      _Pragma("unroll")                                                                      \
      for (int f = 0; f < 4; ++f){                                                           \
        s += xa[f] * winK[f * DP + xc];                                                      \
        s += xv[f] * winK[(f + 4) * DP + xc];                                                \
      }                                                                                      \
      s = fmaxf(s, 0.f);                                                                     \
      xb[buf][sw(row, xc, DP)] = (_Float16)s;                                                \
    } }

// output heads, parallel over all 512 threads: 4 partial-K threads per output,
// reduced via shfl_xor over lane bits 2..3. HBUF = h2 buffer of step tt.
#define OUT_HEAD(tt, HBUF)                                                                   \
  { float s = 0.f;                                                                           \
    _Pragma("unroll")                                                                        \
    for (int kb = 0; kb < 8; ++kb){                                                          \
      int k0 = sub_o * 64 + kb * 8;                                                          \
      hfrag vh = *reinterpret_cast<const hfrag*>(&(HBUF)[sw(orow_o, k0, HH)]);               \
      _Pragma("unroll")                                                                      \
      for (int q = 0; q < 8; ++q){                                                           \
        s += (float)vh[q] * whead[(k0 + q) * 4 + ooc_o];                                     \
      }                                                                                      \
    }                                                                                        \
    s += __shfl_xor(s, 4);                                                                   \
    s += __shfl_xor(s, 8);                                                                   \
    if (sub_o == 0){                                                                         \
      s += hbias;                                                                            \
      if (ooc_o >= 2) s = fmaxf(s, 0.f);                                                     \
      out[(long)(r0 + orow_o) * (PP * 4) + (tt) * 4 + ooc_o] = s;                            \
    } }

// (512,1): do NOT cap VGPRs — occupancy is 1 block/CU (grid == CU count);
// acc[4]+accD[4] = 128 AGPRs + arch regs fit the 2-waves/SIMD unified budget.
__global__ __launch_bounds__(NTHR, 1) void lstm_main(
    const float* __restrict__ x,
    const float* __restrict__ w_in_k,
    const float* __restrict__ w_in_b,
    const float* __restrict__ enc_b,
    const float* __restrict__ dec_b,
    const float* __restrict__ mean_k,
    const float* __restrict__ mean_b,
    const float* __restrict__ lv_k,
    const float* __restrict__ lv_b,
    const _Float16* __restrict__ ws,
    float* __restrict__ out)
{
  // DOUBLE-buffered h: step t reads h[t&1], GATE writes h[(t+1)&1] ->
  // no read/write hazard within a step -> ONE barrier per step instead of two.
  __shared__ _Float16 h1[2][ROWS * HH];   // encoder h (2 x 16 KB)
  __shared__ _Float16 h2[2][ROWS * HH];   // decoder h (2 x 16 KB)
  __shared__ _Float16 xb[2][ROWS * DP];   // xp double buffer (8 KB)
  __shared__ float winK[FF * DP];
  __shared__ float whead[HH * 4];         // [k][mean0,mean1,lv0,lv1]

  const int tid  = threadIdx.x;
  const int wid  = tid >> 6;        // wave id = column-quarter (0..7)
  const int lane = tid & 63;
  const int lcol = lane & 31;       // A-row / B-col within 32-tile
  const int lkh  = lane >> 5;       // k-half of fragment
  const int j    = wid * 32 + lcol; // hidden col 0..255 owned by this lane
  const int r0   = blockIdx.x * ROWS;

  const _Float16* enckT  = ws;
  const _Float16* encrkT = ws + 65536;
  const _Float16* deckT  = ws + 327680;
  const _Float16* decrkT = ws + 589824;

  if (tid < FF * DP) winK[tid] = w_in_k[tid];
  if (tid >= 256){
    int k = tid - 256;
    whead[k * 4 + 0] = mean_k[k * 2 + 0];
    whead[k * 4 + 1] = mean_k[k * 2 + 1];
    whead[k * 4 + 2] = lv_k[k * 2 + 0];
    whead[k * 4 + 3] = lv_k[k * 2 + 1];
  }

  const int xc = tid & 63;          // xp column this thread produces
  const int rb = tid >> 6;          // xp row base
  const float bwin = w_in_b[xc];

  const int orow_o = tid >> 4;      // out-head mapping (all 512 threads)
  const int sub_o  = (tid >> 2) & 3;
  const int ooc_o  = tid & 3;
  const float hbias = (ooc_o < 2) ? mean_b[ooc_o] : lv_b[ooc_o - 2];

  const float eb0 = enc_b[0 * HH + j], eb1 = enc_b[1 * HH + j];
  const float eb2 = enc_b[2 * HH + j], eb3 = enc_b[3 * HH + j];
  const float db0 = dec_b[0 * HH + j], db1 = dec_b[1 * HH + j];
  const float db2 = dec_b[2 * HH + j], db3 = dec_b[3 * HH + j];

  f32x16 acc[4];    // per-gate accumulators (32x32 tile)
  f32x16 accD[4];   // decoder constant-input term (enc_h @ dec_k), registers
  float  cst[16];   // lane-local LSTM cell state
  #pragma unroll
  for (int g = 0; g < 4; ++g) acc[g] = zero16();
  #pragma unroll
  for (int r = 0; r < 16; ++r) cst[r] = 0.f;

  __syncthreads();
  STAGE_XP(0, 0);
  __syncthreads();

  // ---------------- encoder: 20 steps, 1 barrier each ----------------
  for (int t = 0; t < TT; ++t){
    MM_STEPA(acc, xb[t & 1], enckT, DP, 4);            // xp_t @ enc_k
    if (t > 0){
      MM_STEPA(acc, h1[t & 1], encrkT, HH, 16);        // h_t @ enc_rk
    }
    if (t + 1 < TT) STAGE_XP(t + 1, (t + 1) & 1);      // global loads overlap MFMA
    GATE_UPDATE(h1[(t + 1) & 1], eb0, eb1, eb2, eb3, 1);  // writes OTHER buffer
    __syncthreads();                                    // h_{t+1} + xp_{t+1} visible
  }

  // ---------------- decoder: 15 steps, 1 barrier each ----------------
  // RepeatVector: enc_h (= h1[0], TT even) @ dec_k computed once into accD.
  #pragma unroll
  for (int g = 0; g < 4; ++g) accD[g] = zero16();
  {
    f32x16* acc = accD;   // alias so MM_STEPA targets accD
    MM_STEPA(acc, h1[0], deckT, HH, 16);
  }
  #pragma unroll
  for (int r = 0; r < 16; ++r) cst[r] = 0.f;

  for (int t = 0; t < PP; ++t){
    #pragma unroll
    for (int g = 0; g < 4; ++g) acc[g] = accD[g];
    if (t > 0){
      MM_STEPA(acc, h2[t & 1], decrkT, HH, 16);        // h_t @ dec_rk
      OUT_HEAD(t - 1, h2[t & 1]);                      // read-read on same buffer
    }
    GATE_UPDATE(h2[(t + 1) & 1], db0, db1, db2, db3, 0);
    __syncthreads();
  }
  OUT_HEAD(PP - 1, h2[PP & 1]);
}

extern "C" void kernel_launch(void* const* d_in, const int* in_sizes, int n_in,
                              void* d_out, int out_size, void* d_ws, size_t ws_size,
                              hipStream_t stream)
{
  const float* x      = (const float*)d_in[0];
  const float* w_in_k = (const float*)d_in[1];
  const float* w_in_b = (const float*)d_in[2];
  const float* enc_k  = (const float*)d_in[3];
  const float* enc_rk = (const float*)d_in[4];
  const float* enc_b  = (const float*)d_in[5];
  const float* dec_k  = (const float*)d_in[6];
  const float* dec_rk = (const float*)d_in[7];
  const float* dec_b  = (const float*)d_in[8];
  const float* mean_k = (const float*)d_in[9];
  const float* mean_b = (const float*)d_in[10];
  const float* lv_k   = (const float*)d_in[11];
  const float* lv_b   = (const float*)d_in[12];
  _Float16* ws        = (_Float16*)d_ws;

  if (ws_size < 1703936) return;   // 851968 f16 weights = 1.625 MB scratch

  wprep<<<dim3(208), dim3(256), 0, stream>>>(enc_k, enc_rk, dec_k, dec_rk, ws);
  lstm_main<<<dim3(NBLK), dim3(NTHR), 0, stream>>>(x, w_in_k, w_in_b, enc_b, dec_b,
                                                   mean_k, mean_b, lv_k, lv_b, ws,
                                                   (float*)d_out);
}